// Round 2
// baseline (132.534 us; speedup 1.0000x reference)
//
#include <hip/hip_runtime.h>
#include <hip/hip_bf16.h>

#define IN_CH 256
#define OUT_CH 256
#define LATENT 512
#define MSCALE (1.0f / 16.0f)   // 1/sqrt(256)

typedef __attribute__((ext_vector_type(8)))  short bf16x8;
typedef __attribute__((ext_vector_type(16))) float f32x16;
typedef unsigned short u16;

__device__ __forceinline__ u16 f2bf(float f) {
  unsigned int x = __float_as_uint(f);
  x += 0x7fffu + ((x >> 16) & 1u);   // round-to-nearest-even
  return (u16)(x >> 16);
}

// async global->LDS, 16B/lane; LDS dst is wave-uniform base + lane*16.
__device__ __forceinline__ void gload_lds16(const u16* g, u16* l) {
#if defined(__has_builtin) && __has_builtin(__builtin_amdgcn_global_load_lds)
  __builtin_amdgcn_global_load_lds(
      (const __attribute__((address_space(1))) unsigned int*)g,
      (__attribute__((address_space(3))) unsigned int*)l, 16, 0, 0);
#else
  int lane = __builtin_amdgcn_mbcnt_hi(~0u, __builtin_amdgcn_mbcnt_lo(~0u, 0));
  ((uint4*)l)[lane] = *(const uint4*)g;
#endif
}

// ---- kernel 1: mod[b][i]=(1+style)*SCALE ; demod[b][o]=rsqrt(sum mod^2*wsq) --
__global__ void k_style_demod(const float* __restrict__ w, const float* __restrict__ sw,
                              const float* __restrict__ sb, const float* __restrict__ wsq,
                              float* __restrict__ mod, float* __restrict__ demod) {
  __shared__ float ws[LATENT];
  __shared__ float m2[IN_CH];
  const int b = blockIdx.x, tid = threadIdx.x;
  ws[tid] = w[b * LATENT + tid];
  ws[tid + 256] = w[b * LATENT + 256 + tid];
  __syncthreads();
  const float4* sr = (const float4*)(sw + (size_t)tid * LATENT);
  const float4* wr = (const float4*)ws;
  float s = 0.f;
#pragma unroll 8
  for (int l = 0; l < LATENT / 4; ++l) {
    float4 a = sr[l], c = wr[l];
    s += a.x * c.x + a.y * c.y + a.z * c.z + a.w * c.w;
  }
  float m = (1.0f + s + sb[tid]) * MSCALE;
  mod[b * IN_CH + tid] = m;
  m2[tid] = m * m;
  __syncthreads();
  float acc = 1e-8f;
  const float* q = wsq + (size_t)tid * IN_CH;
#pragma unroll 4
  for (int i = 0; i < IN_CH; ++i) acc += m2[i] * q[i];
  demod[b * OUT_CH + tid] = rsqrtf(acc);
}

// ---- kernel 2: wsq[o][i] = sum_9 weight^2 ; wb[t][o][i] = bf16(weight) -----
__global__ void k_wsq(const float* __restrict__ weight, float* __restrict__ wsq,
                      u16* __restrict__ wb) {
  const int o = blockIdx.x, i = threadIdx.x;
  const float* wp = weight + ((size_t)o * IN_CH + i) * 9;
  float s = 0.f;
#pragma unroll
  for (int t = 0; t < 9; ++t) {
    float v = wp[t];
    s += v * v;
    wb[((size_t)t * OUT_CH + o) * IN_CH + i] = f2bf(v);
  }
  wsq[o * IN_CH + i] = s;
}

// ---- kernel 3: xs[b][ph][pw][i] = bf16(x*mod), zero-padded 66x66 ----------
__global__ void k_pad(const float* __restrict__ x, const float* __restrict__ mod,
                      u16* __restrict__ xs) {
  const int bid = blockIdx.x;
  const int b = bid / 66, pr = bid - b * 66;
  const int i = threadIdx.x;
  u16* row = xs + (size_t)((b * 66 + pr) * 66) * IN_CH;
  if (pr == 0 || pr == 65) {
    for (int c = 0; c < 66; ++c) row[c * IN_CH + i] = 0;
  } else {
    const float ms = mod[b * IN_CH + i];
    const float4* xp = (const float4*)(x + (size_t)((b * IN_CH + i) * 64 + (pr - 1)) * 64);
    row[i] = 0;
    row[65 * IN_CH + i] = 0;
#pragma unroll
    for (int c4 = 0; c4 < 16; ++c4) {
      float4 v = xp[c4];
      row[(c4 * 4 + 1) * IN_CH + i] = f2bf(v.x * ms);
      row[(c4 * 4 + 2) * IN_CH + i] = f2bf(v.y * ms);
      row[(c4 * 4 + 3) * IN_CH + i] = f2bf(v.z * ms);
      row[(c4 * 4 + 4) * IN_CH + i] = f2bf(v.w * ms);
    }
  }
}

// ---- kernel 4: conv. 2-phase dbuf pipeline, 16-ich chunks, conflict-free LDS.
// LDS X: [buf][10 r][2 g][66 c] slots of 16B (g = 8-ich k-group).
// LDS W: [buf][9 t][2 g][64 o]. Compute lanes read consecutive slots (ol).
__global__ __launch_bounds__(256, 2)
void k_conv(const u16* __restrict__ xs, const u16* __restrict__ wb,
            const float* __restrict__ demod, float* __restrict__ out) {
  __shared__ __align__(16) u16 xlds[2 * 10 * 2 * 66 * 8];  // 42240 B
  __shared__ __align__(16) u16 wlds[2 * 9 * 2 * 64 * 8];   // 36864 B

  const int tid = threadIdx.x;
  const int lane = tid & 63;
  const int wid = tid >> 6;
  const int ol = lane & 31;
  const int hi = lane >> 5;

  const int bid = blockIdx.x;
  const int sbid = ((bid & 7) << 6) | (bid >> 3);  // bijective XCD swizzle (512=8*64)
  const int otile = (sbid & 3) << 6;
  const int hbase = ((sbid >> 2) & 7) << 3;
  const int b = sbid >> 5;

  const u16* xsb = xs + (size_t)((b * 66 + hbase) * 66) * IN_CH;

  // hoisted per-thread staging source offsets (u16 units), invariant over ic
  int xoff[5];
#pragma unroll
  for (int it = 0; it < 5; ++it) {
    int p = it * 256 + tid;
    int r = p / 132, rem = p - r * 132;
    int g = rem / 66, c = rem - g * 66;
    xoff[it] = (r * 66 + c) * IN_CH + g * 8;
  }
  const int xofft = (9 * 66 + 26 + tid) * IN_CH + 8;           // p=1280+tid: r=9,g=1,c=26+tid
  int woff[4];
#pragma unroll
  for (int it = 0; it < 4; ++it) {
    int p = it * 256 + tid;
    int t = p >> 7, g = (p >> 6) & 1, o = p & 63;
    woff[it] = (t * OUT_CH + otile + o) * IN_CH + g * 8;
  }
  const int wofft = (8 * OUT_CH + otile + (tid & 63)) * IN_CH + ((tid >> 6) & 1) * 8;

  auto stage = [&](int buf, int ic) {
    const int ib = ic * 16;
    u16* xd = xlds + buf * 10560;
#pragma unroll
    for (int it = 0; it < 5; ++it)
      gload_lds16(xsb + xoff[it] + ib, xd + (size_t)(it * 256 + wid * 64) * 8);
    if (tid < 40)
      gload_lds16(xsb + xofft + ib, xd + (size_t)(1280 + wid * 64) * 8);
    u16* wd = wlds + buf * 9216;
#pragma unroll
    for (int it = 0; it < 4; ++it)
      gload_lds16(wb + woff[it] + ib, wd + (size_t)(it * 256 + wid * 64) * 8);
    if (tid < 128)
      gload_lds16(wb + wofft + ib, wd + (size_t)(1024 + wid * 64) * 8);
  };

  f32x16 acc[2][4] = {};

  stage(0, 0);
  __syncthreads();

#pragma unroll 2
  for (int ic = 0; ic < 16; ++ic) {
    const int buf = ic & 1;
    if (ic < 15) stage(buf ^ 1, ic + 1);     // prefetch next chunk (overlaps compute)
    const u16* xp = xlds + buf * 10560;
    const u16* wp = wlds + buf * 9216;
    __builtin_amdgcn_s_setprio(1);
#pragma unroll
    for (int t = 0; t < 9; ++t) {
      const int dh = t / 3, dw = t - dh * 3;
      bf16x8 a0 = *(const bf16x8*)(wp + (size_t)((t * 2 + hi) * 64 + ol) * 8);
      bf16x8 a1 = *(const bf16x8*)(wp + (size_t)((t * 2 + hi) * 64 + 32 + ol) * 8);
#pragma unroll
      for (int ps = 0; ps < 4; ++ps) {
        const int r = 2 * wid + (ps >> 1) + dh;          // padded local row 0..9
        const int c = (ps & 1) * 32 + ol + dw;           // padded col 0..65
        bf16x8 bf = *(const bf16x8*)(xp + (size_t)((r * 2 + hi) * 66 + c) * 8);
        acc[0][ps] = __builtin_amdgcn_mfma_f32_32x32x16_bf16(a0, bf, acc[0][ps], 0, 0, 0);
        acc[1][ps] = __builtin_amdgcn_mfma_f32_32x32x16_bf16(a1, bf, acc[1][ps], 0, 0, 0);
      }
    }
    __builtin_amdgcn_s_setprio(0);
    __syncthreads();   // drains stage loads; protects buf for next overwrite
  }

  // ---- epilogue: out = acc * demod[b][o]
  const float* dmb = demod + b * OUT_CH + otile;
  float* outb = out + (size_t)b * OUT_CH * 4096;
#pragma unroll
  for (int os = 0; os < 2; ++os) {
    float dm[16];
#pragma unroll
    for (int qd = 0; qd < 4; ++qd) {
      float4 d4 = *(const float4*)(dmb + os * 32 + qd * 8 + hi * 4);
      dm[qd * 4 + 0] = d4.x; dm[qd * 4 + 1] = d4.y;
      dm[qd * 4 + 2] = d4.z; dm[qd * 4 + 3] = d4.w;
    }
#pragma unroll
    for (int ps = 0; ps < 4; ++ps) {
      const int prow = hbase + 2 * wid + (ps >> 1);
      const int col = (ps & 1) * 32 + ol;
#pragma unroll
      for (int rr = 0; rr < 16; ++rr) {
        const int orow = (rr & 3) + 8 * (rr >> 2) + 4 * hi;  // C/D row map (m74/m101)
        const int o = otile + os * 32 + orow;
        outb[(size_t)o * 4096 + prow * 64 + col] = acc[os][ps][rr] * dm[rr];
      }
    }
  }
}

extern "C" void kernel_launch(void* const* d_in, const int* in_sizes, int n_in,
                              void* d_out, int out_size, void* d_ws, size_t ws_size,
                              hipStream_t stream) {
  const float* x  = (const float*)d_in[0];   // [16,256,64,64]
  const float* w  = (const float*)d_in[1];   // [16,512]
  const float* sw = (const float*)d_in[2];   // [256,512]
  const float* sb = (const float*)d_in[3];   // [256]
  const float* wt = (const float*)d_in[4];   // [1,256,256,3,3]
  float* out = (float*)d_out;

  char* ws = (char*)d_ws;
  u16*   xs    = (u16*)(ws);                  // 35,684,352 B : padded bf16 x*mod
  u16*   wb    = (u16*)(ws + 35684352);       //  1,179,648 B : bf16 weights [t][o][i]
  float* mod   = (float*)(ws + 36864000);     //     16,384 B
  float* demod = (float*)(ws + 36880384);     //     16,384 B
  float* wsq   = (float*)(ws + 36896768);     //    262,144 B   (total 37,158,912)
  if (ws_size < 37158912u) return;

  k_wsq        <<<256, 256, 0, stream>>>(wt, wsq, wb);
  k_style_demod<<<16, 256, 0, stream>>>(w, sw, sb, wsq, mod, demod);
  k_pad        <<<16 * 66, 256, 0, stream>>>(x, mod, xs);
  k_conv       <<<512, 256, 0, stream>>>(xs, wb, demod, out);
}

// Round 3
// 113.397 us; speedup vs baseline: 1.1688x; 1.1688x over previous
//
#include <hip/hip_runtime.h>
#include <hip/hip_bf16.h>

#define IN_CH 256
#define OUT_CH 256
#define LATENT 512
#define MSCALE (1.0f / 16.0f)   // 1/sqrt(256)

typedef __attribute__((ext_vector_type(8)))  short bf16x8;
typedef __attribute__((ext_vector_type(16))) float f32x16;
typedef unsigned short u16;

__device__ __forceinline__ u16 f2bf(float f) {
  unsigned int x = __float_as_uint(f);
  x += 0x7fffu + ((x >> 16) & 1u);   // round-to-nearest-even
  return (u16)(x >> 16);
}

// async global->LDS, 16B/lane; LDS dst is wave-uniform base + lane*16.
__device__ __forceinline__ void gload_lds16(const u16* g, u16* l) {
#if defined(__has_builtin) && __has_builtin(__builtin_amdgcn_global_load_lds)
  __builtin_amdgcn_global_load_lds(
      (const __attribute__((address_space(1))) unsigned int*)g,
      (__attribute__((address_space(3))) unsigned int*)l, 16, 0, 0);
#else
  int lane = __builtin_amdgcn_mbcnt_hi(~0u, __builtin_amdgcn_mbcnt_lo(~0u, 0));
  ((uint4*)l)[lane] = *(const uint4*)g;
#endif
}

// ---- kernel 1: mod[b][i]=(1+style)*SCALE ; demod[b][o]=rsqrt(sum mod^2*wsq) --
__global__ void k_style_demod(const float* __restrict__ w, const float* __restrict__ sw,
                              const float* __restrict__ sb, const float* __restrict__ wsq,
                              float* __restrict__ mod, float* __restrict__ demod) {
  __shared__ float ws[LATENT];
  __shared__ float m2[IN_CH];
  const int b = blockIdx.x, tid = threadIdx.x;
  ws[tid] = w[b * LATENT + tid];
  ws[tid + 256] = w[b * LATENT + 256 + tid];
  __syncthreads();
  const float4* sr = (const float4*)(sw + (size_t)tid * LATENT);
  const float4* wr = (const float4*)ws;
  float s = 0.f;
#pragma unroll 8
  for (int l = 0; l < LATENT / 4; ++l) {
    float4 a = sr[l], c = wr[l];
    s += a.x * c.x + a.y * c.y + a.z * c.z + a.w * c.w;
  }
  float m = (1.0f + s + sb[tid]) * MSCALE;
  mod[b * IN_CH + tid] = m;
  m2[tid] = m * m;
  __syncthreads();
  float acc = 1e-8f;
  const float* q = wsq + (size_t)tid * IN_CH;
#pragma unroll 4
  for (int i = 0; i < IN_CH; ++i) acc += m2[i] * q[i];
  demod[b * OUT_CH + tid] = rsqrtf(acc);
}

// ---- kernel 2: wsq[o][i]=sum_9 w^2 ; wb[t][G][o][8j]=bf16(w)  (G=i>>3,j=i&7)
__global__ void k_wsq(const float* __restrict__ weight, float* __restrict__ wsq,
                      u16* __restrict__ wb) {
  const int o = blockIdx.x, i = threadIdx.x;
  const float* wp = weight + ((size_t)o * IN_CH + i) * 9;
  float s = 0.f;
#pragma unroll
  for (int t = 0; t < 9; ++t) {
    float v = wp[t];
    s += v * v;
    wb[(((size_t)t * 32 + (i >> 3)) * OUT_CH + o) * 8 + (i & 7)] = f2bf(v);
  }
  wsq[o * IN_CH + i] = s;
}

// ---- kernel 3: xs[b][row][G][col][8j] = bf16(x*mod), zero-padded 66x66 -----
// LDS transpose: coalesced f32 reads -> lt[w][i] -> 16B j-packed vector writes.
__global__ void k_pad(const float* __restrict__ x, const float* __restrict__ mod,
                      u16* __restrict__ xs) {
  const int bid = blockIdx.x;
  const int b = bid / 66, pr = bid - b * 66;
  const int tid = threadIdx.x;
  u16* rowbase = xs + (size_t)((b * 66 + pr) * 32) * 528;   // [32 G][66 c][8 j]

  if (pr == 0 || pr == 65) {                 // full zero row: 1056 uint4
    uint4 z = {0, 0, 0, 0};
    uint4* p = (uint4*)rowbase;
#pragma unroll
    for (int it = 0; it < 5; ++it) {
      int idx = it * 256 + tid;
      if (idx < 1056) p[idx] = z;
    }
    return;
  }

  __shared__ __align__(16) u16 lt[64][264];  // [w][i], stride 264 (528B, 16B-mult)
  const int h = pr - 1;

  // phase A: coalesced read + cvt -> LDS transposed
#pragma unroll
  for (int it = 0; it < 16; ++it) {
    const int i = it * 16 + (tid >> 4);
    const int w4 = (tid & 15) * 4;
    float4 v = *(const float4*)(x + (((size_t)(b * IN_CH + i) * 64 + h) * 64 + w4));
    const float m = mod[b * IN_CH + i];
    lt[w4 + 0][i] = f2bf(v.x * m);
    lt[w4 + 1][i] = f2bf(v.y * m);
    lt[w4 + 2][i] = f2bf(v.z * m);
    lt[w4 + 3][i] = f2bf(v.w * m);
  }
  // pad cols c=0, c=65 (16B zero vectors per G)
  if (tid < 64) {
    uint4 z = {0, 0, 0, 0};
    const int G = tid & 31;
    *(uint4*)(rowbase + (size_t)G * 528 + (tid < 32 ? 0 : 65 * 8)) = z;
  }
  __syncthreads();

  // phase B: 16B j-packed vectors, 128B-contiguous per 8 lanes
  const int G = tid >> 3, wlo = tid & 7;
#pragma unroll
  for (int k = 0; k < 8; ++k) {
    const int w = k * 8 + wlo;
    *(bf16x8*)(rowbase + (size_t)G * 528 + (w + 1) * 8) = *(const bf16x8*)(&lt[w][G * 8]);
  }
}

// ---- kernel 4: conv. 2-phase dbuf pipeline, 16-ich chunks, conflict-free LDS,
// coalesced gload_lds staging (xs/wb are [.. ][G][..][8j]-packed).
__global__ __launch_bounds__(256, 2)
void k_conv(const u16* __restrict__ xs, const u16* __restrict__ wb,
            const float* __restrict__ demod, float* __restrict__ out) {
  __shared__ __align__(16) u16 xlds[2 * 10 * 2 * 66 * 8];  // 42240 B
  __shared__ __align__(16) u16 wlds[2 * 9 * 2 * 64 * 8];   // 36864 B

  const int tid = threadIdx.x;
  const int lane = tid & 63;
  const int wid = tid >> 6;
  const int ol = lane & 31;
  const int hi = lane >> 5;

  const int bid = blockIdx.x;
  const int sbid = ((bid & 7) << 6) | (bid >> 3);  // bijective XCD swizzle (512=8*64)
  const int otile = (sbid & 3) << 6;
  const int hbase = ((sbid >> 2) & 7) << 3;
  const int b = sbid >> 5;

  const u16* xsb = xs + (size_t)((b * 66 + hbase) * 32) * 528;

  // staging source offsets (u16 units); chunk ic adds ic*1056 (X) / ic*4096 (W)
  int xoff[5];
#pragma unroll
  for (int it = 0; it < 5; ++it) {
    int q = it * 256 + tid;
    int r = q / 132, rem = q - r * 132;
    int g = rem / 66, c = rem - g * 66;
    xoff[it] = (r * 32 + g) * 528 + c * 8;
  }
  const int xofft = (9 * 32 + 1) * 528 + (26 + tid) * 8;   // q=1280+tid: r=9,g=1,c=26+tid
  int woff[4];
#pragma unroll
  for (int it = 0; it < 4; ++it) {
    int p = it * 256 + tid;
    int t = p >> 7, g = (p >> 6) & 1, o = p & 63;
    woff[it] = ((t * 32 + g) * OUT_CH + otile + o) * 8;
  }
  const int wofft = ((8 * 32 + ((tid >> 6) & 1)) * OUT_CH + otile + (tid & 63)) * 8;

  auto stage = [&](int buf, int ic) {
    const int ibx = ic * 1056;    // 2 G-groups * 528
    const int ibw = ic * 4096;    // 2 G-groups * 2048
    u16* xd = xlds + buf * 10560;
#pragma unroll
    for (int it = 0; it < 5; ++it)
      gload_lds16(xsb + xoff[it] + ibx, xd + (size_t)(it * 256 + wid * 64) * 8);
    if (tid < 40)
      gload_lds16(xsb + xofft + ibx, xd + (size_t)(1280 + wid * 64) * 8);
    u16* wd = wlds + buf * 9216;
#pragma unroll
    for (int it = 0; it < 4; ++it)
      gload_lds16(wb + woff[it] + ibw, wd + (size_t)(it * 256 + wid * 64) * 8);
    if (tid < 128)
      gload_lds16(wb + wofft + ibw, wd + (size_t)(1024 + wid * 64) * 8);
  };

  f32x16 acc[2][4] = {};

  stage(0, 0);
  __syncthreads();

  for (int ic = 0; ic < 16; ++ic) {
    const int buf = ic & 1;
    if (ic < 15) stage(buf ^ 1, ic + 1);     // prefetch next chunk (overlaps compute)
    const u16* xp = xlds + buf * 10560;
    const u16* wp = wlds + buf * 9216;
    __builtin_amdgcn_s_setprio(1);
#pragma unroll
    for (int t = 0; t < 9; ++t) {
      const int dh = t / 3, dw = t - dh * 3;
      bf16x8 a0 = *(const bf16x8*)(wp + (size_t)((t * 2 + hi) * 64 + ol) * 8);
      bf16x8 a1 = *(const bf16x8*)(wp + (size_t)((t * 2 + hi) * 64 + 32 + ol) * 8);
#pragma unroll
      for (int ps = 0; ps < 4; ++ps) {
        const int r = 2 * wid + (ps >> 1) + dh;          // padded local row 0..9
        const int c = (ps & 1) * 32 + ol + dw;           // padded col 0..65
        bf16x8 bf = *(const bf16x8*)(xp + (size_t)((r * 2 + hi) * 66 + c) * 8);
        acc[0][ps] = __builtin_amdgcn_mfma_f32_32x32x16_bf16(a0, bf, acc[0][ps], 0, 0, 0);
        acc[1][ps] = __builtin_amdgcn_mfma_f32_32x32x16_bf16(a1, bf, acc[1][ps], 0, 0, 0);
      }
    }
    __builtin_amdgcn_s_setprio(0);
    __syncthreads();   // stage loads landed long ago; protects buf for overwrite
  }

  // ---- epilogue: out = acc * demod[b][o]
  const float* dmb = demod + b * OUT_CH + otile;
  float* outb = out + (size_t)b * OUT_CH * 4096;
#pragma unroll
  for (int os = 0; os < 2; ++os) {
    float dm[16];
#pragma unroll
    for (int qd = 0; qd < 4; ++qd) {
      float4 d4 = *(const float4*)(dmb + os * 32 + qd * 8 + hi * 4);
      dm[qd * 4 + 0] = d4.x; dm[qd * 4 + 1] = d4.y;
      dm[qd * 4 + 2] = d4.z; dm[qd * 4 + 3] = d4.w;
    }
#pragma unroll
    for (int ps = 0; ps < 4; ++ps) {
      const int prow = hbase + 2 * wid + (ps >> 1);
      const int col = (ps & 1) * 32 + ol;
#pragma unroll
      for (int rr = 0; rr < 16; ++rr) {
        const int orow = (rr & 3) + 8 * (rr >> 2) + 4 * hi;  // C/D row map (m74/m101)
        const int o = otile + os * 32 + orow;
        outb[(size_t)o * 4096 + prow * 64 + col] = acc[os][ps][rr] * dm[rr];
      }
    }
  }
}

extern "C" void kernel_launch(void* const* d_in, const int* in_sizes, int n_in,
                              void* d_out, int out_size, void* d_ws, size_t ws_size,
                              hipStream_t stream) {
  const float* x  = (const float*)d_in[0];   // [16,256,64,64]
  const float* w  = (const float*)d_in[1];   // [16,512]
  const float* sw = (const float*)d_in[2];   // [256,512]
  const float* sb = (const float*)d_in[3];   // [256]
  const float* wt = (const float*)d_in[4];   // [1,256,256,3,3]
  float* out = (float*)d_out;

  char* ws = (char*)d_ws;
  u16*   xs    = (u16*)(ws);                  // 35,684,352 B : padded bf16 x*mod
  u16*   wb    = (u16*)(ws + 35684352);       //  1,179,648 B : bf16 weights [t][G][o][8]
  float* mod   = (float*)(ws + 36864000);     //     16,384 B
  float* demod = (float*)(ws + 36880384);     //     16,384 B
  float* wsq   = (float*)(ws + 36896768);     //    262,144 B   (total 37,158,912)
  if (ws_size < 37158912u) return;

  k_wsq        <<<256, 256, 0, stream>>>(wt, wsq, wb);
  k_style_demod<<<16, 256, 0, stream>>>(w, sw, sb, wsq, mod, demod);
  k_pad        <<<16 * 66, 256, 0, stream>>>(x, mod, xs);
  k_conv       <<<512, 256, 0, stream>>>(xs, wb, demod, out);
}